// Round 1
// baseline (593.596 us; speedup 1.0000x reference)
//
#include <hip/hip_runtime.h>
#include <cstddef>

// Problem constants (B, C, D, H, W) = (2, 2, 128, 256, 256)
#define BZ   2
#define DV   128
#define HV   256
#define WV   256
#define NP   32      // N_PAIRS
#define NIT  10      // N_ITERS
#define RAD  10      // support radius after NIT pool steps
#define BOX  21      // 2*RAD+1
#define BOX3 (BOX*BOX*BOX)      // 9261
#define ZRAD 11      // zero-init radius (reads extend to RAD+1)
#define ZBOX 23
#define ZBOX3 (ZBOX*ZBOX*ZBOX)  // 12167
#define HWV  (HV*WV)            // 65536
#define DHW  ((size_t)DV*HWV)   // 8388608
#define SMOOTH 1e-5

// ---------------------------------------------------------------------------
// Zero the radius-11 boxes around every seed in both ping-pong buffers, and
// zero the gmax scratch. Overlapping boxes redundantly write 0 — benign.
__global__ void zero_kernel(const int* __restrict__ ea,
                            float* __restrict__ buf0, float* __restrict__ buf1,
                            float* __restrict__ gmax) {
    if (blockIdx.x == 0 && blockIdx.y == 0 && blockIdx.z == 0 &&
        threadIdx.x < 2 * NIT + 4)
        gmax[threadIdx.x] = 0.f;

    int b = blockIdx.z, p = blockIdx.y;
    int t = blockIdx.x * blockDim.x + threadIdx.x;
    if (t >= ZBOX3) return;
    const int* e = ea + (b * NP + p) * 3;
    int dz = t / (ZBOX * ZBOX), r = t % (ZBOX * ZBOX);
    int dy = r / ZBOX, dx = r % ZBOX;
    int d = e[0] + dz - ZRAD;
    int h = e[1] + dy - ZRAD;
    int w = e[2] + dx - ZRAD;
    if (d < 0 || d >= DV || h < 0 || h >= HV || w < 0 || w >= WV) return;
    size_t idx = (size_t)b * DHW + (size_t)d * HWV + (size_t)h * WV + w;
    buf0[idx] = 0.f;
    buf1[idx] = 0.f;
}

// ---------------------------------------------------------------------------
// Set heat = 1.0 at the 32 seed points per batch (duplicates also write 1.0,
// matching .set(1.0) semantics). Must run after zero_kernel (same stream).
__global__ void seed_kernel(const int* __restrict__ ea, float* __restrict__ buf0) {
    int t = threadIdx.x;           // 64 threads: (b, p)
    int b = t / NP, p = t % NP;
    const int* e = ea + (b * NP + p) * 3;
    buf0[(size_t)b * DHW + (size_t)e[0] * HWV + (size_t)e[1] * WV + e[2]] = 1.0f;
}

// ---------------------------------------------------------------------------
// One unnormalized step: hout = avgpool3(hin) * sigmoid(l1 - l0), computed
// only on the radius-10 boxes around seeds (the exact support superset).
// Also reduces the per-batch global max of hout into gmax[it*2 + b].
// Overlapping boxes compute bit-identical values -> benign write races, and
// duplicates don't affect the max.
__global__ void pool_kernel(const float* __restrict__ hin,
                            float* __restrict__ hout,
                            const float* __restrict__ logits,
                            const int* __restrict__ ea,
                            float* __restrict__ gmax, int it) {
    int b = blockIdx.z, p = blockIdx.y;
    int t = blockIdx.x * blockDim.x + threadIdx.x;
    float val = 0.f;
    if (t < BOX3) {
        const int* e = ea + (b * NP + p) * 3;
        int dz = t / (BOX * BOX), r = t % (BOX * BOX);
        int dy = r / BOX, dx = r % BOX;
        int d = e[0] + dz - RAD;
        int h = e[1] + dy - RAD;
        int w = e[2] + dx - RAD;
        if (d >= 0 && d < DV && h >= 0 && h < HV && w >= 0 && w < WV) {
            const float* base = hin + (size_t)b * DHW;
            float s = 0.f;
            #pragma unroll
            for (int zz = -1; zz <= 1; ++zz) {
                int dd = d + zz;
                if (dd < 0 || dd >= DV) continue;
                #pragma unroll
                for (int yy = -1; yy <= 1; ++yy) {
                    int hh = h + yy;
                    if (hh < 0 || hh >= HV) continue;
                    #pragma unroll
                    for (int xx = -1; xx <= 1; ++xx) {
                        int ww = w + xx;
                        if (ww < 0 || ww >= WV) continue;
                        s += base[(size_t)dd * HWV + (size_t)hh * WV + ww];
                    }
                }
            }
            size_t off = (size_t)d * HWV + (size_t)h * WV + w;
            const float* lg = logits + (size_t)b * 2 * DHW;
            float l0 = lg[off], l1 = lg[off + DHW];
            float prob = 1.f / (1.f + expf(l0 - l1));   // softmax(C=2)[1]
            val = s * (1.f / 27.f) * prob;
            hout[(size_t)b * DHW + off] = val;
        }
    }
    // Block max reduction (values >= 0). 256 threads = 4 waves.
    #pragma unroll
    for (int o = 32; o > 0; o >>= 1)
        val = fmaxf(val, __shfl_down(val, o));
    __shared__ float smax[4];
    int wave = threadIdx.x >> 6;
    if ((threadIdx.x & 63) == 0) smax[wave] = val;
    __syncthreads();
    if (threadIdx.x == 0) {
        float m = fmaxf(fmaxf(smax[0], smax[1]), fmaxf(smax[2], smax[3]));
        // Non-negative floats order-preserve as uints.
        atomicMax((unsigned int*)(gmax + it * 2 + b), __float_as_uint(m));
    }
}

// ---------------------------------------------------------------------------
// Final gather: replay the scalar normalization recurrence
//   s_k = s_{k-1} / (s_{k-1}*gmax_k + SMOOTH)   if s_{k-1}*gmax_k > 0
// then scores = s * u_final[eb];  out = 1 - mean(scores).
// eb points farther than RAD (L-inf) from every seed have heat exactly 0
// (and their workspace voxels were never zeroed -> must not be read).
__global__ void gather_kernel(const float* __restrict__ hfinal,
                              const float* __restrict__ gmax,
                              const int* __restrict__ ea,
                              const int* __restrict__ eb,
                              float* __restrict__ out) {
    int t = threadIdx.x;           // 64 threads = 1 wave: (b, p)
    int b = t / NP, p = t % NP;
    const int* e = eb + (b * NP + p) * 3;
    int d = e[0], h = e[1], w = e[2];
    bool inr = false;
    for (int q = 0; q < NP; ++q) {
        const int* a = ea + (b * NP + q) * 3;
        if (abs(d - a[0]) <= RAD && abs(h - a[1]) <= RAD && abs(w - a[2]) <= RAD) {
            inr = true;
            break;
        }
    }
    float val = inr ? hfinal[(size_t)b * DHW + (size_t)d * HWV + (size_t)h * WV + w]
                    : 0.f;
    double s = 1.0;
    for (int k = 0; k < NIT; ++k) {
        double g = (double)gmax[k * 2 + b];
        double den = s * g;
        if (den > 0.0) s = s / (den + SMOOTH);
    }
    float score = (float)(s * (double)val);
    #pragma unroll
    for (int o = 32; o > 0; o >>= 1)
        score += __shfl_down(score, o);
    if (t == 0) out[0] = 1.f - score / (float)(BZ * NP);
}

// ---------------------------------------------------------------------------
extern "C" void kernel_launch(void* const* d_in, const int* in_sizes, int n_in,
                              void* d_out, int out_size, void* d_ws, size_t ws_size,
                              hipStream_t stream) {
    const float* logits = (const float*)d_in[0];
    // d_in[1] = labels (unused; only used host-side to pick endpoints)
    const int* ea = (const int*)d_in[2];
    const int* eb = (const int*)d_in[3];
    float* out = (float*)d_out;

    float* buf0 = (float*)d_ws;                 // BZ*DHW floats (64 MiB)
    float* buf1 = buf0 + BZ * DHW;              // BZ*DHW floats (64 MiB)
    float* gmax = buf1 + BZ * DHW;              // 2*NIT+4 floats

    dim3 zgrid((ZBOX3 + 255) / 256, NP, BZ);
    zero_kernel<<<zgrid, 256, 0, stream>>>(ea, buf0, buf1, gmax);
    seed_kernel<<<1, 64, 0, stream>>>(ea, buf0);

    dim3 pgrid((BOX3 + 255) / 256, NP, BZ);
    float* bufs[2] = {buf0, buf1};
    for (int k = 1; k <= NIT; ++k) {
        pool_kernel<<<pgrid, 256, 0, stream>>>(bufs[(k - 1) & 1], bufs[k & 1],
                                               logits, ea, gmax, k - 1);
    }
    gather_kernel<<<1, 64, 0, stream>>>(bufs[NIT & 1], gmax, ea, eb, out);
}